// Round 8
// baseline (141.594 us; speedup 1.0000x reference)
//
#include <hip/hip_runtime.h>
#include <hip/hip_bf16.h>
#include <math.h>

// NT-Xent loss, N=8192, D=256. Two kernels; k_sim barrier-free + LDS-free
// (B frags share the A-frag lane layout -> loaded directly from global).
// R8 changes vs R7 (85us, MfmaUtil 15%, latency-starved at 2 waves/SIMD):
//  1) XCD-LOCAL B: block reads its physical XCD id (s_getreg HW_REG_XCC_ID,
//     HW-verified on gfx950) and claims col-slice cs==xcc via atomic ticket
//     pools (cyclic-scan overflow => every (cs,rt) pair claimed exactly once
//     for ANY xcc values -- correctness independent of dispatch mapping).
//     Each XCD re-reads only its own 512KB B slice from LOCAL L2.
//  2) bfrag register double-buffer: jt+1 loads issue before jt compute ->
//     load latency hides under MFMA+exp of previous tile.
// History: R1 64x64 spill 77 | R2 168-budget spill 82 | R3 LDS 4x-dup 49.5 |
//   R4 64KB-DMA drains 88 | R5 coop no-op | R6 dbuf-LDS lockstep 91 |
//   R7 direct-global 85 (all pipes <16% busy: pure latency).
#define N_ROWS 8192
#define D_DIM  256
#define HALF_N 4096
#define INV_T      14.285714285714286f      // 1/0.07
#define SCALE_LOG2 20.609929155556620f      // log2(e)/0.07
#define NEG_SCALE  -20.609929155556620f
#define EPSV   1e-8f
#define GRID_SIM 512

typedef __attribute__((ext_vector_type(8))) short bf16x8;   // 8 bf16 = 4 VGPR
typedef __attribute__((ext_vector_type(4))) float f32x4;

__device__ inline unsigned short f2bf(float x) {
    unsigned int u = __float_as_uint(x);
    unsigned int r = (u + 0x7fffu + ((u >> 16) & 1u)) >> 16;   // RNE
    return (unsigned short)r;
}

// ---------------- kernel 1: normalize + exact pos + zero accumulators ------
// fbf layout is fragment-tiled: byte = (row>>4)*8192 + (k>>3)*256
//   + (row&15)*16 + (k&7)*2  -> wave frag loads are 1KB-contiguous.
__global__ __launch_bounds__(256) void k_norm(const float* __restrict__ feat,
                                              char* __restrict__ fbf,
                                              float* __restrict__ sumexp,
                                              float* __restrict__ pos,
                                              unsigned int* __restrict__ meta) {
    const int tid = threadIdx.x;
    const int gid = blockIdx.x * 256 + tid;
    if (gid < N_ROWS) sumexp[gid] = 0.f;
    if (gid < 16) meta[gid] = 0u;          // [0..7] ticket pools, [8] counter

    const int w = tid >> 6, lane = tid & 63;
    const int row = blockIdx.x * 4 + w;              // 2048 blocks * 4 rows
    const int pc  = (row + HALF_N) & (N_ROWS - 1);
    const float4 v = ((const float4*)(feat + row * D_DIM))[lane];
    const float4 p = ((const float4*)(feat + pc  * D_DIM))[lane];
    float ss  = v.x*v.x + v.y*v.y + v.z*v.z + v.w*v.w;
    float sp  = p.x*p.x + p.y*p.y + p.z*p.z + p.w*p.w;
    float dot = v.x*p.x + v.y*p.y + v.z*p.z + v.w*p.w;
    #pragma unroll
    for (int off = 32; off; off >>= 1) {
        ss  += __shfl_xor(ss,  off);
        sp  += __shfl_xor(sp,  off);
        dot += __shfl_xor(dot, off);
    }
    const float scale = 1.f / fmaxf(sqrtf(ss), EPSV);
    ushort4 o;
    o.x = f2bf(v.x * scale);
    o.y = f2bf(v.y * scale);
    o.z = f2bf(v.z * scale);
    o.w = f2bf(v.w * scale);
    *(ushort4*)(fbf + (size_t)(row >> 4) * 8192 + (lane >> 1) * 256
                    + (row & 15) * 16 + (lane & 1) * 8) = o;
    if (lane == 0)
        pos[row] = dot / (fmaxf(sqrtf(ss), EPSV) * fmaxf(sqrtf(sp), EPSV));
}

// ---------------- kernel 2 helpers -----------------------------------------
__device__ inline void load_bfrags(bf16x8 bf[8], const char* bp, int jt) {
    #pragma unroll
    for (int t = 0; t < 8; ++t)
        bf[t] = *(const bf16x8*)(bp + (size_t)jt * 8192 + t * 1024);
}

__device__ inline void compute_tile(const bf16x8 afrag[8][4], const bf16x8 bf[8],
                                    float rsum[4][4], int rowBase, int tcol,
                                    int q, int l15) {
    f32x4 acc[4];
    #pragma unroll
    for (int ri = 0; ri < 4; ++ri) acc[ri] = (f32x4){0.f, 0.f, 0.f, 0.f};
    #pragma unroll
    for (int t = 0; t < 8; ++t)
        #pragma unroll
        for (int ri = 0; ri < 4; ++ri)
            acc[ri] = __builtin_amdgcn_mfma_f32_16x16x32_bf16(
                afrag[t][ri], bf[t], acc[ri], 0, 0, 0);
    // C/D layout: col=l15, row=q*4+reg. Diagonal 16x16 tile test wave-uniform.
    #pragma unroll
    for (int ri = 0; ri < 4; ++ri) {
        const int trow = rowBase + ri * 16;
        if (trow == tcol) {
            #pragma unroll
            for (int r = 0; r < 4; ++r) {
                const float e = __builtin_amdgcn_exp2f(
                    __builtin_fmaf(acc[ri][r], SCALE_LOG2, NEG_SCALE));
                rsum[ri][r] += (q * 4 + r == l15) ? 0.f : e;
            }
        } else {
            #pragma unroll
            for (int r = 0; r < 4; ++r)
                rsum[ri][r] += __builtin_amdgcn_exp2f(
                    __builtin_fmaf(acc[ri][r], SCALE_LOG2, NEG_SCALE));
        }
    }
}

// ---------------- kernel 2: XCD-local barrier-free sim ---------------------
__global__ __launch_bounds__(256, 2) void k_sim(const char* __restrict__ fbf,
                                                float* __restrict__ sumexp,
                                                const float* __restrict__ pos,
                                                unsigned int* __restrict__ meta,
                                                float* __restrict__ out) {
    __shared__ float redbuf[4];
    __shared__ int s_rt, s_cs, isLast;
    const int tid  = threadIdx.x;
    const int lane = tid & 63;
    const int w    = tid >> 6;
    const int q    = lane >> 4, l15 = lane & 15;

    // claim a (cs, rt) work item; prefer cs == this block's physical XCD
    if (tid == 0) {
        unsigned int xcc = 0;
        asm volatile("s_getreg_b32 %0, hwreg(HW_REG_XCC_ID)" : "=s"(xcc));
        int rt = 0, cs = 0;
        #pragma unroll 1
        for (int k = 0; k < 8; ++k) {
            cs = (int)((xcc + k) & 7u);
            const unsigned int r = atomicAdd(&meta[cs], 1u);
            if (r < 64u) { rt = (int)r; break; }
        }
        s_rt = rt; s_cs = cs;
    }
    __syncthreads();
    const int rt = s_rt, cs = s_cs;
    const int rowBase  = rt * 128 + (w >> 1) * 64;
    const int colBase0 = cs * 1024 + (w & 1) * 512;

    const size_t laneOff = (size_t)q * 256 + (size_t)l15 * 16;
    const char* bp = fbf + (size_t)(colBase0 / 16) * 8192 + laneOff;

    // A fragments: rows rowBase + ri*16 + l15, k = t*32 + q*8 + j (128 regs)
    bf16x8 afrag[8][4];
    #pragma unroll
    for (int ri = 0; ri < 4; ++ri) {
        const char* ap = fbf + (size_t)(rowBase / 16 + ri) * 8192 + laneOff;
        #pragma unroll
        for (int t = 0; t < 8; ++t)
            afrag[t][ri] = *(const bf16x8*)(ap + t * 1024);
    }

    float rsum[4][4];
    #pragma unroll
    for (int ri = 0; ri < 4; ++ri)
        #pragma unroll
        for (int r = 0; r < 4; ++r) rsum[ri][r] = 0.f;

    // 32 x 16-col tiles, register double-buffered: loads for jt+1 are in
    // flight while tile jt computes (no barriers anywhere).
    bf16x8 bA[8], bB[8];
    load_bfrags(bA, bp, 0);
    #pragma unroll 1
    for (int jt = 0; jt < 32; jt += 2) {
        load_bfrags(bB, bp, jt + 1);
        compute_tile(afrag, bA, rsum, rowBase, colBase0 + jt * 16, q, l15);
        if (jt + 2 < 32) load_bfrags(bA, bp, jt + 2);
        compute_tile(afrag, bB, rsum, rowBase, colBase0 + (jt + 1) * 16, q, l15);
    }

    // quad-reduce (cols) then one atomic per row per wave
    #pragma unroll
    for (int ri = 0; ri < 4; ++ri)
        #pragma unroll
        for (int r = 0; r < 4; ++r) {
            float s = rsum[ri][r];
            s += __shfl_xor(s, 1);
            s += __shfl_xor(s, 2);
            s += __shfl_xor(s, 4);
            s += __shfl_xor(s, 8);
            if (l15 == 0)
                atomicAdd(&sumexp[rowBase + ri * 16 + q * 4 + r], s);
        }

    // -------- last block computes mean NLL (device-scope handoff) ---------
    __threadfence();
    if (tid == 0) {
        unsigned int prev = __hip_atomic_fetch_add(&meta[8], 1u, __ATOMIC_ACQ_REL,
                                                   __HIP_MEMORY_SCOPE_AGENT);
        isLast = (prev == GRID_SIM - 1);
    }
    __syncthreads();
    if (isLast) {
        float accn = 0.f;
        for (int i = tid; i < N_ROWS; i += 256) {
            const float se = __hip_atomic_load(&sumexp[i], __ATOMIC_RELAXED,
                                               __HIP_MEMORY_SCOPE_AGENT);
            accn += logf(se) - pos[i] * INV_T;
        }
        #pragma unroll
        for (int off = 32; off; off >>= 1) accn += __shfl_xor(accn, off);
        if (lane == 0) redbuf[w] = accn;
        __syncthreads();
        if (tid == 0)
            out[0] = INV_T + (redbuf[0] + redbuf[1] + redbuf[2] + redbuf[3])
                             * (1.f / N_ROWS);
    }
}

extern "C" void kernel_launch(void* const* d_in, const int* in_sizes, int n_in,
                              void* d_out, int out_size, void* d_ws, size_t ws_size,
                              hipStream_t stream) {
    const float* feat = (const float*)d_in[0];
    char* ws = (char*)d_ws;
    char* fbf     = ws;                                              // 4 MB bf16
    float* sumexp = (float*)(ws + 4u*1024u*1024u);                   // 32 KB
    float* pos    = (float*)(ws + 4u*1024u*1024u + 32u*1024u);       // 32 KB
    unsigned int* meta = (unsigned int*)(ws + 4u*1024u*1024u + 64u*1024u);

    k_norm<<<N_ROWS / 4, 256, 0, stream>>>(feat, fbf, sumexp, pos, meta);
    k_sim <<<GRID_SIM,   256, 0, stream>>>(fbf, sumexp, pos, meta,
                                           (float*)d_out);
}